// Round 17
// baseline (144.348 us; speedup 1.0000x reference)
//
#include <hip/hip_runtime.h>

#define NQ 32768
#define NP 8192
#define FD 32
#define KNN 8
#define QW 4                 // queries per wave
#define WPB 8                // waves per block
#define TB 512
#define QBLK (QW * WPB)      // 32 queries per block
#define ABLK 2048            // phase-A sample points (stride-4 of original order)
#define CAP 128              // candidate capacity (E~33, r12/r13-validated stats)
#define NB 256               // z-bins

typedef unsigned long long u64;

__device__ __forceinline__ int binof(float z) {
    int b = (int)floorf((z + 5.0f) * 25.6f);     // monotone (RNE mul by +const), clamped
    return min(NB - 1, max(0, b));
}

__device__ __forceinline__ u64 shfl_xor_u64(u64 k, int j) {
    unsigned lo = __shfl_xor((unsigned)k, j);
    unsigned hi = __shfl_xor((unsigned)(k >> 32), j);
    return ((u64)hi << 32) | lo;
}
__device__ __forceinline__ u64 sort64_u64(u64 key, int lane) {   // r5-verified
    for (int k2 = 2; k2 <= 64; k2 <<= 1)
        for (int j = k2 >> 1; j > 0; j >>= 1) {
            u64 o = shfl_xor_u64(key, j);
            bool keepMin = ((lane & k2) == 0) == ((lane & j) == 0);
            key = ((o < key) == keepMin) ? o : key;
        }
    return key;
}
__device__ __forceinline__ float eighth_smallest64(float v, int lane) {  // r6-verified
    for (int k2 = 2; k2 <= 64; k2 <<= 1)
        for (int j = k2 >> 1; j > 0; j >>= 1) {
            float o = __shfl_xor(v, j);
            bool keepMin = ((lane & k2) == 0) == ((lane & j) == 0);
            v = ((o < v) == keepMin) ? o : v;
        }
    return __uint_as_float((unsigned)__builtin_amdgcn_readlane((int)__float_as_uint(v), 7));
}

// ---- prep 1: z-histograms for points & queries; phase-A sample pack ----
__global__ void k_hist(const float* __restrict__ xyz, const float* __restrict__ points,
                       unsigned* __restrict__ pcnt, unsigned* __restrict__ qcnt,
                       float4* __restrict__ pts4a) {
    int t = blockIdx.x * 256 + threadIdx.x;
    if (t < NP) atomicAdd(&pcnt[binof(points[t * 3 + 2])], 1u);
    if (t < NQ) atomicAdd(&qcnt[binof(xyz[t * 3 + 2])], 1u);
    if (t < ABLK) {
        int i = t * 4;                        // strided sample of actual points
        float px = points[i * 3 + 0], py = points[i * 3 + 1], pz = points[i * 3 + 2];
        float pn = __builtin_fmaf(pz, pz, __builtin_fmaf(py, py, px * px));
        pts4a[t] = make_float4(-2.0f * px, -2.0f * py, -2.0f * pz, pn);
    }
}

// ---- prep 2: exclusive scans (single block); cnt arrays become scatter cursors ----
__global__ __launch_bounds__(256) void k_scan(unsigned* __restrict__ pcnt, unsigned* __restrict__ pstart,
                                              unsigned* __restrict__ qcnt, unsigned* __restrict__ qstart) {
    __shared__ unsigned sh[NB];
    int t = threadIdx.x;
    sh[t] = pcnt[t]; __syncthreads();
    for (int off = 1; off < NB; off <<= 1) {
        unsigned v = (t >= off) ? sh[t - off] : 0; __syncthreads();
        sh[t] += v; __syncthreads();
    }
    unsigned ex = t ? sh[t - 1] : 0;
    pstart[t] = ex; if (t == NB - 1) pstart[NB] = sh[NB - 1];
    pcnt[t] = ex;
    __syncthreads();
    sh[t] = qcnt[t]; __syncthreads();
    for (int off = 1; off < NB; off <<= 1) {
        unsigned v = (t >= off) ? sh[t - off] : 0; __syncthreads();
        sh[t] += v; __syncthreads();
    }
    unsigned qex = t ? sh[t - 1] : 0;
    qstart[t] = qex; if (t == NB - 1) qstart[NB] = sh[NB - 1];
    qcnt[t] = qex;
}

// ---- prep 3: scatter points (packed, z-sorted) + original idx; scatter query ids ----
__global__ void k_scatter(const float* __restrict__ xyz, const float* __restrict__ points,
                          unsigned* __restrict__ pcur, unsigned* __restrict__ qcur,
                          float4* __restrict__ pts4s, unsigned short* __restrict__ pidxs,
                          unsigned* __restrict__ qids) {
    int t = blockIdx.x * 256 + threadIdx.x;
    if (t < NP) {
        float px = points[t * 3 + 0], py = points[t * 3 + 1], pz = points[t * 3 + 2];
        float pn = __builtin_fmaf(pz, pz, __builtin_fmaf(py, py, px * px));
        unsigned pos = atomicAdd(&pcur[binof(pz)], 1u);
        pts4s[pos] = make_float4(-2.0f * px, -2.0f * py, -2.0f * pz, pn);
        pidxs[pos] = (unsigned short)t;
    }
    if (t < NQ) {
        unsigned pos = atomicAdd(&qcur[binof(xyz[t * 3 + 2])], 1u);
        qids[pos] = (unsigned)t;
    }
}

__global__ __launch_bounds__(TB) void knn_kernel(
    const float* __restrict__ xyz, const float* __restrict__ points,
    const float* __restrict__ feats, const float4* __restrict__ pts4a,
    const float4* __restrict__ pts4s, const unsigned short* __restrict__ pidxs,
    const unsigned* __restrict__ pstart, const unsigned* __restrict__ qids,
    float* __restrict__ out)
{
#pragma clang fp contract(off)   // np-exact paths: explicit mul/add; fast paths: explicit fmaf
    __shared__ unsigned short sidx16[QBLK * CAP]; // 8 KB candidate indices (wave-private)
    __shared__ int scnt[QBLK];

    const int t     = threadIdx.x;
    const int lane  = t & 63;
    const int wid   = t >> 6;
    const int qbase = blockIdx.x * QBLK + wid * QW;  // position in SORTED query order

    if (lane < QW) scnt[wid * QW + lane] = 0;
    __syncthreads();

    unsigned qid[QW];
    float qx[QW], qy[QW], qz[QW], qn[QW], mn[QW], tscr[QW];
#pragma unroll
    for (int qq = 0; qq < QW; ++qq) {
        unsigned q = qids[qbase + qq];
        qid[qq] = q;
        float a = xyz[q * 3 + 0], b = xyz[q * 3 + 1], c = xyz[q * 3 + 2];
        qx[qq] = a; qy[qq] = b; qz[qq] = c;
        qn[qq] = (a * a + b * b) + c * c;   // np-exact: rounded squares, sequential add
        mn[qq] = __builtin_inff();
    }

    // ---- Phase A: min-stream over the 2048-point sample (coalesced, L2-resident) ----
#pragma unroll 4
    for (int s = 0; s < ABLK / 64; ++s) {
        float4 p = pts4a[s * 64 + lane];
#pragma unroll
        for (int qq = 0; qq < QW; ++qq) {
            float g = __builtin_fmaf(qx[qq], p.x,
                      __builtin_fmaf(qy[qq], p.y,
                      __builtin_fmaf(qz[qq], p.z, p.w)));
            mn[qq] = fminf(mn[qq], g);
        }
    }
    // tight valid bound (r6-verified argument: 64 lane-mins of disjoint actual-point
    // subsets; 8th smallest upper-bounds the full-set 8th smallest)
#pragma unroll
    for (int qq = 0; qq < QW; ++qq)
        tscr[qq] = eighth_smallest64(mn[qq], lane) + 1e-3f;  // margin >> g-vs-np-d2 gap

    // ---- slab: wave-uniform z-range covering all 4 queries' 8-NN balls ----
    float zlo = __builtin_inff(), zhi = -__builtin_inff();
#pragma unroll
    for (int qq = 0; qq < QW; ++qq) {
        float r2 = fmaxf(qn[qq] + tscr[qq] + 2e-3f, 0.0f);  // d8 bound + slop
        float r  = sqrtf(r2) + 1e-4f;
        zlo = fminf(zlo, qz[qq] - r);
        zhi = fmaxf(zhi, qz[qq] + r);
    }
    int lo = (int)pstart[binof(zlo)];
    int hi = (int)pstart[binof(zhi) + 1];

    // ---- Phase B: screen only the slab range of z-sorted points ----
    for (int i = lo + lane; i < hi; i += 64) {
        float4 p = pts4s[i];
#pragma unroll
        for (int qq = 0; qq < QW; ++qq) {
            float g = __builtin_fmaf(qx[qq], p.x,
                      __builtin_fmaf(qy[qq], p.y,
                      __builtin_fmaf(qz[qq], p.z, p.w)));
            if (__builtin_expect(g <= tscr[qq], 0)) {
                int oi = pidxs[i];                       // original index (rare load)
                int wq = wid * QW + qq;
                int slot = atomicAdd(&scnt[wq], 1);
                if (slot < CAP) sidx16[wq * CAP + slot] = (unsigned short)oi;
            }
        }
    }
    // wave-private lists; no block barrier needed (atomics order same-wave LDS)

    // ---- Phase C: np-exact d2 recompute, u64 sort(s), top-8, output (r10-16 verified) ----
    const float4* feats4 = (const float4*)feats;
    float4* outf4 = (float4*)(out + (long)NQ * KNN * 3);
#pragma unroll 1
    for (int qq = 0; qq < QW; ++qq) {
        int wq = wid * QW + qq;
        int q  = (int)qid[qq];                 // ORIGINAL query id
        int cnt = scnt[wq]; if (cnt > CAP) cnt = CAP;

        u64 key1 = ~0ull;
        if (lane < cnt) {
            int idx = sidx16[wq * CAP + lane];
            float px = points[idx * 3 + 0], py = points[idx * 3 + 1], pz = points[idx * 3 + 2];
            float pn  = (px * px + py * py) + pz * pz;                 // np-exact
            float dot = __builtin_fmaf(qz[qq], pz, __builtin_fmaf(qy[qq], py, qx[qq] * px));
            float d2v = (qn[qq] - 2.0f * dot) + pn;
            unsigned bb = __float_as_uint(d2v);
            unsigned mk = (bb & 0x80000000u) ? ~bb : (bb | 0x80000000u);  // monotone map
            key1 = ((u64)mk << 32) | (unsigned)idx;                       // (value, stable idx)
        }
        u64 v = sort64_u64(key1, lane);

        if (cnt > 64) {                       // wave-uniform, rare (mean cnt ~33)
            u64 key2 = ~0ull;
            if (lane + 64 < cnt) {
                int idx = sidx16[wq * CAP + 64 + lane];
                float px = points[idx * 3 + 0], py = points[idx * 3 + 1], pz = points[idx * 3 + 2];
                float pn  = (px * px + py * py) + pz * pz;
                float dot = __builtin_fmaf(qz[qq], pz, __builtin_fmaf(qy[qq], py, qx[qq] * px));
                float d2v = (qn[qq] - 2.0f * dot) + pn;
                unsigned bb = __float_as_uint(d2v);
                unsigned mk = (bb & 0x80000000u) ? ~bb : (bb | 0x80000000u);
                key2 = ((u64)mk << 32) | (unsigned)idx;
            }
            u64 s2 = sort64_u64(key2, lane);
            int src = (15 - lane) & 63;
            unsigned lo2 = __shfl((unsigned)s2, src);
            unsigned hi2 = __shfl((unsigned)(s2 >> 32), src);
            u64 kr = ((u64)hi2 << 32) | lo2;
            u64 m = (lane < 8) ? v : ((lane < 16) ? kr : ~0ull);
#pragma unroll
            for (int j = 8; j > 0; j >>= 1) {
                u64 o = shfl_xor_u64(m, j);
                bool low = (lane & j) == 0;
                m = low ? (o < m ? o : m) : (o < m ? m : o);
            }
            v = m;
        }

        // lanes 0..7 hold top-8 ascending (r5/r6-verified output layout)
        int nb = __shfl((int)(unsigned)v, lane >> 3);
        outf4[(long)q * (KNN * FD / 4) + lane] = feats4[(long)nb * (FD / 4) + (lane & 7)];
        int j2 = lane / 3;
        int nb2 = __shfl((int)(unsigned)v, j2);
        if (lane < 24) {
            out[(long)q * (KNN * 3) + lane] = points[nb2 * 3 + (lane - j2 * 3)];
        }
    }
}

extern "C" void kernel_launch(void* const* d_in, const int* in_sizes, int n_in,
                              void* d_out, int out_size, void* d_ws, size_t ws_size,
                              hipStream_t stream) {
    const float* xyz    = (const float*)d_in[0];
    const float* points = (const float*)d_in[1];
    const float* feats  = (const float*)d_in[2];
    float* out = (float*)d_out;

    char* ws = (char*)d_ws;
    float4*         pts4a  = (float4*)(ws);                    //  32 KB
    float4*         pts4s  = (float4*)(ws + 32768);            // 128 KB
    unsigned*       qids   = (unsigned*)(ws + 163840);         // 128 KB
    unsigned short* pidxs  = (unsigned short*)(ws + 294912);   //  16 KB
    unsigned*       pcnt   = (unsigned*)(ws + 311296);         // 1 KB
    unsigned*       pstart = (unsigned*)(ws + 312320);         // 1028 B
    unsigned*       qcnt   = (unsigned*)(ws + 313348);         // 1 KB
    unsigned*       qstart = (unsigned*)(ws + 314372);         // 1028 B

    hipMemsetAsync(ws + 311296, 0, 315400 - 311296, stream);
    hipLaunchKernelGGL(k_hist,    dim3(NQ / 256), dim3(256), 0, stream, xyz, points, pcnt, qcnt, pts4a);
    hipLaunchKernelGGL(k_scan,    dim3(1),        dim3(256), 0, stream, pcnt, pstart, qcnt, qstart);
    hipLaunchKernelGGL(k_scatter, dim3(NQ / 256), dim3(256), 0, stream, xyz, points, pcnt, qcnt,
                       pts4s, pidxs, qids);
    hipLaunchKernelGGL(knn_kernel, dim3(NQ / QBLK), dim3(TB), 0, stream,
                       xyz, points, feats, pts4a, pts4s, pidxs, pstart, qids, out);
}

// Round 18
// 121.036 us; speedup vs baseline: 1.1926x; 1.1926x over previous
//
#include <hip/hip_runtime.h>

#define NQ 32768
#define NP 8192
#define FD 32
#define KNN 8
#define QW 4                 // queries per wave
#define WPB 8                // waves per block
#define TB 512
#define QBLK (QW * WPB)      // 32 queries per block
#define ABLK 2048            // phase-A sample points (stride-4 of original order)
#define CAP 128              // candidate capacity (E~33, r12-r17-validated stats)
#define NB 256               // z-bins

typedef unsigned long long u64;

__device__ __forceinline__ int binof(float z) {
    int b = (int)floorf((z + 5.0f) * 25.6f);     // monotone, clamped (r17-verified)
    return min(NB - 1, max(0, b));
}

__device__ __forceinline__ u64 shfl_xor_u64(u64 k, int j) {
    unsigned lo = __shfl_xor((unsigned)k, j);
    unsigned hi = __shfl_xor((unsigned)(k >> 32), j);
    return ((u64)hi << 32) | lo;
}
__device__ __forceinline__ u64 sort64_u64(u64 key, int lane) {   // r5-verified
    for (int k2 = 2; k2 <= 64; k2 <<= 1)
        for (int j = k2 >> 1; j > 0; j >>= 1) {
            u64 o = shfl_xor_u64(key, j);
            bool keepMin = ((lane & k2) == 0) == ((lane & j) == 0);
            key = ((o < key) == keepMin) ? o : key;
        }
    return key;
}
__device__ __forceinline__ float eighth_smallest64(float v, int lane) {  // r6-verified
    for (int k2 = 2; k2 <= 64; k2 <<= 1)
        for (int j = k2 >> 1; j > 0; j >>= 1) {
            float o = __shfl_xor(v, j);
            bool keepMin = ((lane & k2) == 0) == ((lane & j) == 0);
            v = ((o < v) == keepMin) ? o : v;
        }
    return __uint_as_float((unsigned)__builtin_amdgcn_readlane((int)__float_as_uint(v), 7));
}

// ---- fused prep (single block, 1024 threads): LDS hist -> LDS scan -> scatter ----
__global__ __launch_bounds__(1024) void k_prep(
        const float* __restrict__ xyz, const float* __restrict__ points,
        float4* __restrict__ pts4a, float4* __restrict__ pts4s,
        unsigned short* __restrict__ pidxs, unsigned* __restrict__ qids,
        unsigned* __restrict__ pstart) {
    __shared__ unsigned ph[NB], qh[NB], pc[NB], qc[NB];
    const int t = threadIdx.x;
    if (t < NB) { ph[t] = 0; qh[t] = 0; }
    __syncthreads();
    for (int i = t; i < NP; i += 1024) atomicAdd(&ph[binof(points[i * 3 + 2])], 1u);
    for (int i = t; i < NQ; i += 1024) atomicAdd(&qh[binof(xyz[i * 3 + 2])], 1u);
    for (int i = t; i < ABLK; i += 1024) {        // phase-A sample pack (stride-4)
        int j = i * 4;
        float px = points[j * 3 + 0], py = points[j * 3 + 1], pz = points[j * 3 + 2];
        float pn = __builtin_fmaf(pz, pz, __builtin_fmaf(py, py, px * px));
        pts4a[i] = make_float4(-2.0f * px, -2.0f * py, -2.0f * pz, pn);
    }
    __syncthreads();
    for (int off = 1; off < NB; off <<= 1) {      // inclusive Hillis-Steele scans
        unsigned pv = 0, qv = 0;
        if (t < NB && t >= off) { pv = ph[t - off]; qv = qh[t - off]; }
        __syncthreads();
        if (t < NB && t >= off) { ph[t] += pv; qh[t] += qv; }
        __syncthreads();
    }
    if (t < NB) {
        unsigned pe = t ? ph[t - 1] : 0;
        unsigned qe = t ? qh[t - 1] : 0;
        pc[t] = pe; qc[t] = qe;
        pstart[t] = pe;
    }
    if (t == 0) pstart[NB] = ph[NB - 1];
    __syncthreads();
    for (int i = t; i < NP; i += 1024) {          // scatter points (z-sorted, packed)
        float px = points[i * 3 + 0], py = points[i * 3 + 1], pz = points[i * 3 + 2];
        float pn = __builtin_fmaf(pz, pz, __builtin_fmaf(py, py, px * px));
        unsigned pos = atomicAdd(&pc[binof(pz)], 1u);
        pts4s[pos] = make_float4(-2.0f * px, -2.0f * py, -2.0f * pz, pn);
        pidxs[pos] = (unsigned short)i;
    }
    for (int i = t; i < NQ; i += 1024) {          // scatter query ids (z-sorted)
        unsigned pos = atomicAdd(&qc[binof(xyz[i * 3 + 2])], 1u);
        qids[pos] = (unsigned)i;
    }
}

__global__ __launch_bounds__(TB) void knn_kernel(
    const float* __restrict__ xyz, const float* __restrict__ points,
    const float* __restrict__ feats, const float4* __restrict__ pts4a,
    const float4* __restrict__ pts4s, const unsigned short* __restrict__ pidxs,
    const unsigned* __restrict__ pstart, const unsigned* __restrict__ qids,
    float* __restrict__ out)
{
#pragma clang fp contract(off)   // np-exact paths: explicit mul/add; fast paths: explicit fmaf
    __shared__ unsigned short sidx16[QBLK * CAP]; // 8 KB candidate indices (wave-private)
    __shared__ int scnt[QBLK];

    const int t     = threadIdx.x;
    const int lane  = t & 63;
    const int wid   = t >> 6;
    const int qbase = blockIdx.x * QBLK + wid * QW;  // position in SORTED query order

    if (lane < QW) scnt[wid * QW + lane] = 0;   // wave-private: no block barrier needed

    unsigned qid[QW];
    float qx[QW], qy[QW], qz[QW], qn[QW], mn[QW], tscr[QW];
#pragma unroll
    for (int qq = 0; qq < QW; ++qq) {
        unsigned q = qids[qbase + qq];
        qid[qq] = q;
        float a = xyz[q * 3 + 0], b = xyz[q * 3 + 1], c = xyz[q * 3 + 2];
        qx[qq] = a; qy[qq] = b; qz[qq] = c;
        qn[qq] = (a * a + b * b) + c * c;   // np-exact: rounded squares, sequential add
        mn[qq] = __builtin_inff();
    }

    // ---- Phase A: min-stream over the 2048-point sample (coalesced, L2-resident) ----
#pragma unroll 4
    for (int s = 0; s < ABLK / 64; ++s) {
        float4 p = pts4a[s * 64 + lane];
#pragma unroll
        for (int qq = 0; qq < QW; ++qq) {
            float g = __builtin_fmaf(qx[qq], p.x,
                      __builtin_fmaf(qy[qq], p.y,
                      __builtin_fmaf(qz[qq], p.z, p.w)));
            mn[qq] = fminf(mn[qq], g);
        }
    }
    // tight valid bound (r6-verified sub-multiset order-statistic argument)
#pragma unroll
    for (int qq = 0; qq < QW; ++qq)
        tscr[qq] = eighth_smallest64(mn[qq], lane) + 1e-3f;  // margin >> g-vs-np-d2 gap

    // ---- slab: wave-uniform z-range covering all 4 queries' 8-NN balls (r17-verified) ----
    float zlo = __builtin_inff(), zhi = -__builtin_inff();
#pragma unroll
    for (int qq = 0; qq < QW; ++qq) {
        float r2 = fmaxf(qn[qq] + tscr[qq] + 2e-3f, 0.0f);
        float r  = sqrtf(r2) + 1e-4f;
        zlo = fminf(zlo, qz[qq] - r);
        zhi = fmaxf(zhi, qz[qq] + r);
    }
    const int lo = (int)pstart[binof(zlo)];
    const int hi = (int)pstart[binof(zhi) + 1];

    // ---- Phase B: screen the slab with 4-deep prefetch (4 loads in flight) ----
    for (int base = lo + lane; base < hi; base += 256) {
        float4 p0, p1, p2, p3;
        {
            int i0 = base;
            int i1 = min(base + 64,  hi - 1);
            int i2 = min(base + 128, hi - 1);
            int i3 = min(base + 192, hi - 1);
            p0 = pts4s[i0]; p1 = pts4s[i1]; p2 = pts4s[i2]; p3 = pts4s[i3];
        }
#pragma unroll
        for (int j = 0; j < 4; ++j) {
            int ii = base + j * 64;
            if (ii >= hi) break;               // wave-near-uniform tail
            float4 p = (j == 0) ? p0 : (j == 1) ? p1 : (j == 2) ? p2 : p3;
#pragma unroll
            for (int qq = 0; qq < QW; ++qq) {
                float g = __builtin_fmaf(qx[qq], p.x,
                          __builtin_fmaf(qy[qq], p.y,
                          __builtin_fmaf(qz[qq], p.z, p.w)));
                if (__builtin_expect(g <= tscr[qq], 0)) {
                    int oi = pidxs[ii];                     // original index (rare load)
                    int wq = wid * QW + qq;
                    int slot = atomicAdd(&scnt[wq], 1);
                    if (slot < CAP) sidx16[wq * CAP + slot] = (unsigned short)oi;
                }
            }
        }
    }
    // wave-private lists; no block barrier needed

    // ---- Phase C: np-exact d2 recompute, u64 sort(s), top-8, output (r10-17 verified) ----
    const float4* feats4 = (const float4*)feats;
    float4* outf4 = (float4*)(out + (long)NQ * KNN * 3);
#pragma unroll 1
    for (int qq = 0; qq < QW; ++qq) {
        int wq = wid * QW + qq;
        int q  = (int)qid[qq];                 // ORIGINAL query id
        int cnt = scnt[wq]; if (cnt > CAP) cnt = CAP;

        u64 key1 = ~0ull;
        if (lane < cnt) {
            int idx = sidx16[wq * CAP + lane];
            float px = points[idx * 3 + 0], py = points[idx * 3 + 1], pz = points[idx * 3 + 2];
            float pn  = (px * px + py * py) + pz * pz;                 // np-exact
            float dot = __builtin_fmaf(qz[qq], pz, __builtin_fmaf(qy[qq], py, qx[qq] * px));
            float d2v = (qn[qq] - 2.0f * dot) + pn;
            unsigned bb = __float_as_uint(d2v);
            unsigned mk = (bb & 0x80000000u) ? ~bb : (bb | 0x80000000u);  // monotone map
            key1 = ((u64)mk << 32) | (unsigned)idx;                       // (value, stable idx)
        }
        u64 v = sort64_u64(key1, lane);

        if (cnt > 64) {                       // wave-uniform, rare (mean cnt ~33)
            u64 key2 = ~0ull;
            if (lane + 64 < cnt) {
                int idx = sidx16[wq * CAP + 64 + lane];
                float px = points[idx * 3 + 0], py = points[idx * 3 + 1], pz = points[idx * 3 + 2];
                float pn  = (px * px + py * py) + pz * pz;
                float dot = __builtin_fmaf(qz[qq], pz, __builtin_fmaf(qy[qq], py, qx[qq] * px));
                float d2v = (qn[qq] - 2.0f * dot) + pn;
                unsigned bb = __float_as_uint(d2v);
                unsigned mk = (bb & 0x80000000u) ? ~bb : (bb | 0x80000000u);
                key2 = ((u64)mk << 32) | (unsigned)idx;
            }
            u64 s2 = sort64_u64(key2, lane);
            int src = (15 - lane) & 63;
            unsigned lo2 = __shfl((unsigned)s2, src);
            unsigned hi2 = __shfl((unsigned)(s2 >> 32), src);
            u64 kr = ((u64)hi2 << 32) | lo2;
            u64 m = (lane < 8) ? v : ((lane < 16) ? kr : ~0ull);
#pragma unroll
            for (int j = 8; j > 0; j >>= 1) {
                u64 o = shfl_xor_u64(m, j);
                bool low = (lane & j) == 0;
                m = low ? (o < m ? o : m) : (o < m ? m : o);
            }
            v = m;
        }

        // lanes 0..7 hold top-8 ascending (r5/r6-verified output layout)
        int nb = __shfl((int)(unsigned)v, lane >> 3);
        outf4[(long)q * (KNN * FD / 4) + lane] = feats4[(long)nb * (FD / 4) + (lane & 7)];
        int j2 = lane / 3;
        int nb2 = __shfl((int)(unsigned)v, j2);
        if (lane < 24) {
            out[(long)q * (KNN * 3) + lane] = points[nb2 * 3 + (lane - j2 * 3)];
        }
    }
}

extern "C" void kernel_launch(void* const* d_in, const int* in_sizes, int n_in,
                              void* d_out, int out_size, void* d_ws, size_t ws_size,
                              hipStream_t stream) {
    const float* xyz    = (const float*)d_in[0];
    const float* points = (const float*)d_in[1];
    const float* feats  = (const float*)d_in[2];
    float* out = (float*)d_out;

    char* ws = (char*)d_ws;
    float4*         pts4a  = (float4*)(ws);                    //  32 KB
    float4*         pts4s  = (float4*)(ws + 32768);            // 128 KB
    unsigned*       qids   = (unsigned*)(ws + 163840);         // 128 KB
    unsigned short* pidxs  = (unsigned short*)(ws + 294912);   //  16 KB
    unsigned*       pstart = (unsigned*)(ws + 311296);         // 1028 B

    hipLaunchKernelGGL(k_prep, dim3(1), dim3(1024), 0, stream,
                       xyz, points, pts4a, pts4s, pidxs, qids, pstart);
    hipLaunchKernelGGL(knn_kernel, dim3(NQ / QBLK), dim3(TB), 0, stream,
                       xyz, points, feats, pts4a, pts4s, pidxs, pstart, qids, out);
}

// Round 19
// 109.946 us; speedup vs baseline: 1.3129x; 1.1009x over previous
//
#include <hip/hip_runtime.h>

#define NQ 32768
#define NP 8192
#define FD 32
#define KNN 8
#define QW 4                 // queries per wave
#define WPB 8                // waves per block
#define TB 512
#define QBLK (QW * WPB)      // 32 queries per block
#define CHP 1024             // points per staged chunk (512 pairs)
#define CAP 128              // candidate capacity (E~33, r12-r18-validated stats)

typedef unsigned long long u64;
typedef float f32x2 __attribute__((ext_vector_type(2)));

// packed 2-wide fma: per half computes a*b+c — bit-identical to __builtin_fmaf
__device__ __forceinline__ f32x2 pkfma(f32x2 a, f32x2 b, f32x2 c) {
    f32x2 d;
    asm("v_pk_fma_f32 %0, %1, %2, %3" : "=v"(d) : "v"(a), "v"(b), "v"(c));
    return d;
}

__device__ __forceinline__ u64 shfl_xor_u64(u64 k, int j) {
    unsigned lo = __shfl_xor((unsigned)k, j);
    unsigned hi = __shfl_xor((unsigned)(k >> 32), j);
    return ((u64)hi << 32) | lo;
}
__device__ __forceinline__ u64 sort64_u64(u64 key, int lane) {   // r5-verified
    for (int k2 = 2; k2 <= 64; k2 <<= 1)
        for (int j = k2 >> 1; j > 0; j >>= 1) {
            u64 o = shfl_xor_u64(key, j);
            bool keepMin = ((lane & k2) == 0) == ((lane & j) == 0);
            key = ((o < key) == keepMin) ? o : key;
        }
    return key;
}
__device__ __forceinline__ float eighth_smallest64(float v, int lane) {  // r6-verified
    for (int k2 = 2; k2 <= 64; k2 <<= 1)
        for (int j = k2 >> 1; j > 0; j >>= 1) {
            float o = __shfl_xor(v, j);
            bool keepMin = ((lane & k2) == 0) == ((lane & j) == 0);
            v = ((o < v) == keepMin) ? o : v;
        }
    return __uint_as_float((unsigned)__builtin_amdgcn_readlane((int)__float_as_uint(v), 7));
}

// prepack: pts4[i] = (-2x, -2y, -2z, pn_screen) — screen-space only (Phase C re-derives
// np-exact values from the original points array)
__global__ void k_prepack(const float* __restrict__ points, float4* __restrict__ pts4) {
    int i = blockIdx.x * blockDim.x + threadIdx.x;   // grid exactly NP
    float px = points[i * 3 + 0], py = points[i * 3 + 1], pz = points[i * 3 + 2];
    float pn = __builtin_fmaf(pz, pz, __builtin_fmaf(py, py, px * px));
    pts4[i] = make_float4(-2.0f * px, -2.0f * py, -2.0f * pz, pn);
}

__global__ __launch_bounds__(TB) void knn_kernel(
    const float* __restrict__ xyz, const float* __restrict__ points,
    const float* __restrict__ feats, const float4* __restrict__ pts4,
    float* __restrict__ out)
{
#pragma clang fp contract(off)   // np-exact paths: explicit mul/add; fast paths: explicit fmaf/pk
    __shared__ f32x2 sX[CHP / 2], sY[CHP / 2], sZ[CHP / 2], sW[CHP / 2]; // 16 KB pair-SoA
    __shared__ unsigned short sidx16[QBLK * CAP];                        // 8 KB
    __shared__ int scnt[QBLK];

    const int t     = threadIdx.x;
    const int lane  = t & 63;
    const int wid   = t >> 6;
    const int qbase = blockIdx.x * QBLK + wid * QW;

    if (t < QBLK) scnt[t] = 0;

    float qn[QW], mn[QW], tscr[QW];
    float qxs[QW], qys[QW], qzs[QW];
    f32x2 qx2[QW], qy2[QW], qz2[QW];          // splatted once, reused every point-pair
#pragma unroll
    for (int qq = 0; qq < QW; ++qq) {
        int q = qbase + qq;
        float a = xyz[q * 3 + 0], b = xyz[q * 3 + 1], c = xyz[q * 3 + 2];
        qxs[qq] = a; qys[qq] = b; qzs[qq] = c;
        qx2[qq] = (f32x2){a, a}; qy2[qq] = (f32x2){b, b}; qz2[qq] = (f32x2){c, c};
        qn[qq] = (a * a + b * b) + c * c;   // np-exact: rounded squares, sequential add
        mn[qq] = __builtin_inff();
    }

    // stage chunk c into pair-SoA (thread t owns point pair (c*CHP+2t, +1))
#define STAGE(c)  {                                                   \
        float4 pa = pts4[(c) * CHP + 2 * t];                          \
        float4 pb = pts4[(c) * CHP + 2 * t + 1];                      \
        sX[t] = (f32x2){pa.x, pb.x}; sY[t] = (f32x2){pa.y, pb.y};     \
        sZ[t] = (f32x2){pa.z, pb.z}; sW[t] = (f32x2){pa.w, pb.w}; }

    // ---- Phase A: chunks 0,1 min-only (g per half bit-identical to fmaf chain) ----
#pragma unroll 1
    for (int c = 0; c < 2; ++c) {
        __syncthreads();
        STAGE(c);
        __syncthreads();
#pragma unroll 2
        for (int s = 0; s < CHP / 128; ++s) {
            int j = s * 64 + lane;
            f32x2 X = sX[j], Y = sY[j], Z = sZ[j], W = sW[j];
#pragma unroll
            for (int qq = 0; qq < QW; ++qq) {
                f32x2 g = pkfma(X, qx2[qq], pkfma(Y, qy2[qq], pkfma(Z, qz2[qq], W)));
                mn[qq] = fminf(mn[qq], fminf(g[0], g[1]));
            }
        }
    }
    // tight valid bound: 8th-smallest of 64 lane-mins (disjoint 32-point subsets =>
    // 8 distinct actual g-values <= tau => upper-bounds full-set 8th smallest)
#pragma unroll
    for (int qq = 0; qq < QW; ++qq)
        tscr[qq] = eighth_smallest64(mn[qq], lane) + 1e-3f;  // margin >> g-vs-np-d2 gap

    // ---- Phase B: screen all 8 chunks; chunk 1 still resident -> screen first ----
#pragma unroll 1
    for (int k = 0; k < 8; ++k) {
        int c = (k == 0) ? 1 : ((k <= 6) ? k + 1 : 0);
        if (k > 0) {
            __syncthreads();
            STAGE(c);
            __syncthreads();
        }
#pragma unroll 2
        for (int s = 0; s < CHP / 128; ++s) {
            int j = s * 64 + lane;
            f32x2 X = sX[j], Y = sY[j], Z = sZ[j], W = sW[j];
            int bj = c * CHP + 2 * j;
#pragma unroll
            for (int qq = 0; qq < QW; ++qq) {
                f32x2 g = pkfma(X, qx2[qq], pkfma(Y, qy2[qq], pkfma(Z, qz2[qq], W)));
                float gm = fminf(g[0], g[1]);
                if (__builtin_expect(gm <= tscr[qq], 0)) {   // same acceptance set
                    int wq = wid * QW + qq;
                    if (g[0] <= tscr[qq]) {
                        int slot = atomicAdd(&scnt[wq], 1);
                        if (slot < CAP) sidx16[wq * CAP + slot] = (unsigned short)bj;
                    }
                    if (g[1] <= tscr[qq]) {
                        int slot = atomicAdd(&scnt[wq], 1);
                        if (slot < CAP) sidx16[wq * CAP + slot] = (unsigned short)(bj + 1);
                    }
                }
            }
        }
    }
#undef STAGE
    __syncthreads();

    // ---- Phase C: np-exact d2 recompute, u64 sort(s), top-8, output (r10-18 verified) ----
    const float4* feats4 = (const float4*)feats;
    float4* outf4 = (float4*)(out + (long)NQ * KNN * 3);
#pragma unroll 1
    for (int qq = 0; qq < QW; ++qq) {
        int wq = wid * QW + qq;
        int q  = qbase + qq;
        int cnt = scnt[wq]; if (cnt > CAP) cnt = CAP;

        u64 key1 = ~0ull;
        if (lane < cnt) {
            int idx = sidx16[wq * CAP + lane];
            float px = points[idx * 3 + 0], py = points[idx * 3 + 1], pz = points[idx * 3 + 2];
            float pn  = (px * px + py * py) + pz * pz;                 // np-exact
            float dot = __builtin_fmaf(qzs[qq], pz, __builtin_fmaf(qys[qq], py, qxs[qq] * px));
            float d2v = (qn[qq] - 2.0f * dot) + pn;
            unsigned bb = __float_as_uint(d2v);
            unsigned mk = (bb & 0x80000000u) ? ~bb : (bb | 0x80000000u);  // monotone map
            key1 = ((u64)mk << 32) | (unsigned)idx;                       // (value, stable idx)
        }
        u64 v = sort64_u64(key1, lane);

        if (cnt > 64) {                       // wave-uniform, rare (mean cnt ~33)
            u64 key2 = ~0ull;
            if (lane + 64 < cnt) {
                int idx = sidx16[wq * CAP + 64 + lane];
                float px = points[idx * 3 + 0], py = points[idx * 3 + 1], pz = points[idx * 3 + 2];
                float pn  = (px * px + py * py) + pz * pz;
                float dot = __builtin_fmaf(qzs[qq], pz, __builtin_fmaf(qys[qq], py, qxs[qq] * px));
                float d2v = (qn[qq] - 2.0f * dot) + pn;
                unsigned bb = __float_as_uint(d2v);
                unsigned mk = (bb & 0x80000000u) ? ~bb : (bb | 0x80000000u);
                key2 = ((u64)mk << 32) | (unsigned)idx;
            }
            u64 s2 = sort64_u64(key2, lane);
            // lanes 8..15 take s2[15-lane] (descending) -> lanes 0..15 bitonic; 4-step merge
            int src = (15 - lane) & 63;
            unsigned lo2 = __shfl((unsigned)s2, src);
            unsigned hi2 = __shfl((unsigned)(s2 >> 32), src);
            u64 kr = ((u64)hi2 << 32) | lo2;
            u64 m = (lane < 8) ? v : ((lane < 16) ? kr : ~0ull);
#pragma unroll
            for (int j = 8; j > 0; j >>= 1) {
                u64 o = shfl_xor_u64(m, j);
                bool low = (lane & j) == 0;
                m = low ? (o < m ? o : m) : (o < m ? m : o);
            }
            v = m;
        }

        // lanes 0..7 hold top-8 ascending (r5/r6-verified output layout)
        int nb = __shfl((int)(unsigned)v, lane >> 3);
        outf4[(long)q * (KNN * FD / 4) + lane] = feats4[(long)nb * (FD / 4) + (lane & 7)];
        int j2 = lane / 3;
        int nb2 = __shfl((int)(unsigned)v, j2);
        if (lane < 24) {
            out[(long)q * (KNN * 3) + lane] = points[nb2 * 3 + (lane - j2 * 3)];
        }
    }
}

extern "C" void kernel_launch(void* const* d_in, const int* in_sizes, int n_in,
                              void* d_out, int out_size, void* d_ws, size_t ws_size,
                              hipStream_t stream) {
    const float* xyz    = (const float*)d_in[0];
    const float* points = (const float*)d_in[1];
    const float* feats  = (const float*)d_in[2];
    float* out = (float*)d_out;
    float4* pts4 = (float4*)d_ws;   // 128 KB scratch

    hipLaunchKernelGGL(k_prepack, dim3(NP / 256), dim3(256), 0, stream, points, pts4);
    hipLaunchKernelGGL(knn_kernel, dim3(NQ / QBLK), dim3(TB), 0, stream,
                       xyz, points, feats, pts4, out);
}

// Round 20
// 77.600 us; speedup vs baseline: 1.8601x; 1.4168x over previous
//
#include <hip/hip_runtime.h>

#define NQ 32768
#define NP 8192
#define FD 32
#define KNN 8
#define QW 4                 // queries per wave
#define WPB 8                // waves per block
#define TB 512
#define QBLK (QW * WPB)      // 32 queries per block
#define CHP 1024             // points per staged chunk
#define NCH (NP / CHP)       // 8
#define ABLK 2048            // phase-A points (global stream, min-only)
#define CAP 128              // candidate capacity (E~32, r12/r13-validated)

typedef unsigned long long u64;

__device__ __forceinline__ u64 shfl_xor_u64(u64 k, int j) {
    unsigned lo = __shfl_xor((unsigned)k, j);
    unsigned hi = __shfl_xor((unsigned)(k >> 32), j);
    return ((u64)hi << 32) | lo;
}
// full 64-lane bitonic sort, ascending by lane (r5-verified pattern)
__device__ __forceinline__ u64 sort64_u64(u64 key, int lane) {
    for (int k2 = 2; k2 <= 64; k2 <<= 1)
        for (int j = k2 >> 1; j > 0; j >>= 1) {
            u64 o = shfl_xor_u64(key, j);
            bool keepMin = ((lane & k2) == 0) == ((lane & j) == 0);
            key = ((o < key) == keepMin) ? o : key;
        }
    return key;
}
// exact 8th-smallest of the 64 lane values (r6-verified f32 bitonic + readlane 7)
__device__ __forceinline__ float eighth_smallest64(float v, int lane) {
    for (int k2 = 2; k2 <= 64; k2 <<= 1)
        for (int j = k2 >> 1; j > 0; j >>= 1) {
            float o = __shfl_xor(v, j);
            bool keepMin = ((lane & k2) == 0) == ((lane & j) == 0);
            v = ((o < v) == keepMin) ? o : v;
        }
    return __uint_as_float((unsigned)__builtin_amdgcn_readlane((int)__float_as_uint(v), 7));
}

// prepack: pts4[i] = (-2x, -2y, -2z, pn_screen) — screen-space only (Phase C re-derives
// np-exact values from the original points array)
__global__ void k_prepack(const float* __restrict__ points, float4* __restrict__ pts4) {
    int i = blockIdx.x * blockDim.x + threadIdx.x;   // grid exactly NP
    float px = points[i * 3 + 0], py = points[i * 3 + 1], pz = points[i * 3 + 2];
    float pn = __builtin_fmaf(pz, pz, __builtin_fmaf(py, py, px * px));
    pts4[i] = make_float4(-2.0f * px, -2.0f * py, -2.0f * pz, pn);
}

__global__ __launch_bounds__(TB) void knn_kernel(
    const float* __restrict__ xyz, const float* __restrict__ points,
    const float* __restrict__ feats, const float4* __restrict__ pts4,
    float* __restrict__ out)
{
#pragma clang fp contract(off)   // np-exact paths: explicit mul/add; fast paths: explicit fmaf
    __shared__ float4 sp[CHP];                    // 16 KB staged chunk (pure copy of pts4)
    __shared__ unsigned short sidx16[QBLK * CAP]; // 8 KB candidate indices
    __shared__ int scnt[QBLK];

    const int t     = threadIdx.x;
    const int lane  = t & 63;
    const int wid   = t >> 6;
    const int qbase = blockIdx.x * QBLK + wid * QW;

    if (t < QBLK) scnt[t] = 0;

    float qx[QW], qy[QW], qz[QW], qn[QW], mn[QW], tscr[QW];
#pragma unroll
    for (int qq = 0; qq < QW; ++qq) {
        int q = qbase + qq;
        float a = xyz[q * 3 + 0], b = xyz[q * 3 + 1], c = xyz[q * 3 + 2];
        qx[qq] = a; qy[qq] = b; qz[qq] = c;
        qn[qq] = (a * a + b * b) + c * c;   // np-exact: rounded squares, sequential add
        mn[qq] = __builtin_inff();
    }

    // ---- Phase A: global min-only stream over pts4[0..ABLK) (no LDS, no barriers;
    //      8 waves/block + 4 blocks/CU hide the L2 latency) ----
#pragma unroll 4
    for (int s = 0; s < ABLK / 64; ++s) {
        float4 p = pts4[s * 64 + lane];
#pragma unroll
        for (int qq = 0; qq < QW; ++qq) {
            float g = __builtin_fmaf(qx[qq], p.x,
                      __builtin_fmaf(qy[qq], p.y,
                      __builtin_fmaf(qz[qq], p.z, p.w)));
            mn[qq] = fminf(mn[qq], g);
        }
    }
    // tight valid bound: 8th-smallest of 64 lane-mins (disjoint point subsets =>
    // 8 distinct actual g-values <= tau => upper-bounds full-set 8th smallest)
#pragma unroll
    for (int qq = 0; qq < QW; ++qq)
        tscr[qq] = eighth_smallest64(mn[qq], lane) + 1e-3f;  // margin >> g-vs-np-d2 gap

    // ---- Phase B: screen all NP points from LDS-staged chunks (pure copy staging) ----
    for (int c = 0; c < NCH; ++c) {
        __syncthreads();
        for (int i = t; i < CHP; i += TB) sp[i] = pts4[c * CHP + i];   // 16B copy
        __syncthreads();
#pragma unroll 4
        for (int s = 0; s < CHP / 64; ++s) {
            float4 p = sp[s * 64 + lane];
#pragma unroll
            for (int qq = 0; qq < QW; ++qq) {
                float g = __builtin_fmaf(qx[qq], p.x,
                          __builtin_fmaf(qy[qq], p.y,
                          __builtin_fmaf(qz[qq], p.z, p.w)));
                if (__builtin_expect(g <= tscr[qq], 0)) {
                    int wq = wid * QW + qq;
                    int slot = atomicAdd(&scnt[wq], 1);
                    if (slot < CAP) sidx16[wq * CAP + slot] = (unsigned short)(c * CHP + s * 64 + lane);
                }
            }
        }
    }
    __syncthreads();
    // each wave owns its queries' candidate lists from here

    // ---- Phase C: np-exact d2 recompute, u64 sort(s), top-8, output (r10-13 verified) ----
    const float4* feats4 = (const float4*)feats;
    float4* outf4 = (float4*)(out + (long)NQ * KNN * 3);
#pragma unroll 1
    for (int qq = 0; qq < QW; ++qq) {
        int wq = wid * QW + qq;
        int q  = qbase + qq;
        int cnt = scnt[wq]; if (cnt > CAP) cnt = CAP;

        u64 key1 = ~0ull;
        if (lane < cnt) {
            int idx = sidx16[wq * CAP + lane];
            float px = points[idx * 3 + 0], py = points[idx * 3 + 1], pz = points[idx * 3 + 2];
            float pn  = (px * px + py * py) + pz * pz;                 // np-exact
            float dot = __builtin_fmaf(qz[qq], pz, __builtin_fmaf(qy[qq], py, qx[qq] * px));
            float d2v = (qn[qq] - 2.0f * dot) + pn;
            unsigned bb = __float_as_uint(d2v);
            unsigned mk = (bb & 0x80000000u) ? ~bb : (bb | 0x80000000u);  // monotone map
            key1 = ((u64)mk << 32) | (unsigned)idx;                       // (value, stable idx)
        }
        u64 v = sort64_u64(key1, lane);

        if (cnt > 64) {                       // wave-uniform, rare (mean cnt ~32)
            u64 key2 = ~0ull;
            if (lane + 64 < cnt) {
                int idx = sidx16[wq * CAP + 64 + lane];
                float px = points[idx * 3 + 0], py = points[idx * 3 + 1], pz = points[idx * 3 + 2];
                float pn  = (px * px + py * py) + pz * pz;
                float dot = __builtin_fmaf(qz[qq], pz, __builtin_fmaf(qy[qq], py, qx[qq] * px));
                float d2v = (qn[qq] - 2.0f * dot) + pn;
                unsigned bb = __float_as_uint(d2v);
                unsigned mk = (bb & 0x80000000u) ? ~bb : (bb | 0x80000000u);
                key2 = ((u64)mk << 32) | (unsigned)idx;
            }
            u64 s2 = sort64_u64(key2, lane);
            // lanes 8..15 take s2[15-lane] (descending) -> lanes 0..15 bitonic; 4-step merge
            int src = (15 - lane) & 63;
            unsigned lo2 = __shfl((unsigned)s2, src);
            unsigned hi2 = __shfl((unsigned)(s2 >> 32), src);
            u64 kr = ((u64)hi2 << 32) | lo2;
            u64 m = (lane < 8) ? v : ((lane < 16) ? kr : ~0ull);
#pragma unroll
            for (int j = 8; j > 0; j >>= 1) {
                u64 o = shfl_xor_u64(m, j);
                bool low = (lane & j) == 0;
                m = low ? (o < m ? o : m) : (o < m ? m : o);
            }
            v = m;
        }

        // lanes 0..7 hold top-8 ascending (r5/r6-verified output layout)
        int nb = __shfl((int)(unsigned)v, lane >> 3);
        outf4[(long)q * (KNN * FD / 4) + lane] = feats4[(long)nb * (FD / 4) + (lane & 7)];
        int j2 = lane / 3;
        int nb2 = __shfl((int)(unsigned)v, j2);
        if (lane < 24) {
            out[(long)q * (KNN * 3) + lane] = points[nb2 * 3 + (lane - j2 * 3)];
        }
    }
}

extern "C" void kernel_launch(void* const* d_in, const int* in_sizes, int n_in,
                              void* d_out, int out_size, void* d_ws, size_t ws_size,
                              hipStream_t stream) {
    const float* xyz    = (const float*)d_in[0];
    const float* points = (const float*)d_in[1];
    const float* feats  = (const float*)d_in[2];
    float* out = (float*)d_out;
    float4* pts4 = (float4*)d_ws;   // 128 KB scratch

    hipLaunchKernelGGL(k_prepack, dim3(NP / 256), dim3(256), 0, stream, points, pts4);
    hipLaunchKernelGGL(knn_kernel, dim3(NQ / QBLK), dim3(TB), 0, stream,
                       xyz, points, feats, pts4, out);
}